// Round 4
// baseline (400.079 us; speedup 1.0000x reference)
//
#include <hip/hip_runtime.h>
#include <hip/hip_bf16.h>

// Fused QKV projection: qkv = hidden[16384,1024] @ Wqkv[1024,3072] + bias,
// scattered to q/k/v [4,16,4096,64] each, fp32 out.
// R4: RESTRUCTURE. R1-R3 proved the LDS+barrier K-loop is latency-bound
// (true MFMA-pipe busy ~8%, all pipes <50%, vmcnt(0)+s_barrier drain).
// New scheme: convert kernels emit A and B pre-tiled in MFMA fragment order
// [panel32][ks][lane][8]; GEMM loads fragments straight to VGPRs as fully
// coalesced 1KB/wave dwordx4 loads. No LDS, no __syncthreads, prefetch
// distance 2, compiler-managed fine-grained vmcnt.

#define M_TOT 16384
#define N_TOT 3072
#define K_TOT 1024

typedef __bf16 bf16x8 __attribute__((ext_vector_type(8)));
typedef unsigned short ushx8 __attribute__((ext_vector_type(8)));
typedef float f32x16 __attribute__((ext_vector_type(16)));

__device__ __forceinline__ unsigned short f2bf(float f) {
    unsigned int u = __builtin_bit_cast(unsigned int, f);
    u += 0x7fffu + ((u >> 16) & 1u);
    return (unsigned short)(u >> 16);
}

// ---- kernel 1: hidden fp32 -> A_tiled bf16
// A_tiled[panel][ks][lane][j] = A[panel*32 + (lane&31)][ks*16 + (lane>>5)*8 + j]
// (verified fragment mapping for mfma_f32_32x32x16_bf16 A-operand, R3 passed)
// grid: 512 panels x 256 thr; wave w sweeps ks in [w*16, w*16+16).
__global__ void convert_hidden(const float* __restrict__ x,
                               unsigned short* __restrict__ At) {
    const int panel = blockIdx.x;
    const int t = threadIdx.x;
    const int wave = t >> 6, lane = t & 63;
    const int r5 = lane & 31, half = lane >> 5;
    const float* src = x + (size_t)(panel * 32 + r5) * 1024 + half * 8;
    unsigned short* dst = At + (size_t)panel * 32768 + lane * 8;
#pragma unroll 4
    for (int ks = wave * 16; ks < wave * 16 + 16; ++ks) {
        float4 f0 = *(const float4*)(src + ks * 16);
        float4 f1 = *(const float4*)(src + ks * 16 + 4);
        ushx8 o;
        o[0] = f2bf(f0.x); o[1] = f2bf(f0.y); o[2] = f2bf(f0.z); o[3] = f2bf(f0.w);
        o[4] = f2bf(f1.x); o[5] = f2bf(f1.y); o[6] = f2bf(f1.z); o[7] = f2bf(f1.w);
        *(ushx8*)(dst + ks * 512) = o;
    }
}

// ---- kernel 2: W[k][n] fp32 -> Bt_tiled bf16 (transposed into B-frag order)
// Bt_tiled[panel][ks][lane][j] = W[ks*16 + (lane>>5)*8 + j][n0 + (lane&31)]
// grid: 96 panels (3 matrices x 32) x 256 thr.
__global__ void convert_weights(const float* __restrict__ Wq,
                                const float* __restrict__ Wk,
                                const float* __restrict__ Wv,
                                unsigned short* __restrict__ Bt) {
    const int panel = blockIdx.x;
    const int mat = panel >> 5;           // 0,1,2
    const int n0 = (panel & 31) * 32;
    const float* W = (mat == 0) ? Wq : (mat == 1) ? Wk : Wv;
    const int t = threadIdx.x;
    const int wave = t >> 6, lane = t & 63;
    const int r5 = lane & 31, half = lane >> 5;
    const float* src = W + (size_t)half * 8 * 1024 + n0 + r5;
    unsigned short* dst = Bt + (size_t)panel * 32768 + lane * 8;
#pragma unroll 2
    for (int ks = wave * 16; ks < wave * 16 + 16; ++ks) {
        ushx8 o;
#pragma unroll
        for (int j = 0; j < 8; ++j)
            o[j] = f2bf(src[(size_t)(ks * 16 + j) * 1024]);
        *(ushx8*)(dst + ks * 512) = o;
    }
}

// ---- kernel 3: GEMM, no LDS, no barriers.
// Block 256 thr = 4 waves, block tile 128x128, wave tile 64x64 = 2x2 of
// mfma_f32_32x32x16_bf16 over 64 ks-steps of K=16. Fragments loaded直接
// from pre-tiled arrays: 1 KB/wave coalesced dwordx4, prefetch distance 2.
__launch_bounds__(256, 3)
__global__ void qkv_gemm(const unsigned short* __restrict__ At,
                         const unsigned short* __restrict__ Bt,
                         const float* __restrict__ bq,
                         const float* __restrict__ bk,
                         const float* __restrict__ bv,
                         float* __restrict__ out) {
    const int tid  = threadIdx.x;
    const int wave = tid >> 6;
    const int lane = tid & 63;
    const int r5   = lane & 31;
    const int half = lane >> 5;

    const int bm = blockIdx.x;  // 0..127
    const int bn = blockIdx.y;  // 0..23
    const int wr = wave >> 1;   // 0..1
    const int wc = wave & 1;    // 0..1

    // fragment streams: panel stride = 64 ks * 512 ush = 32768
    const unsigned short* pa0 = At + (size_t)(bm * 4 + wr * 2 + 0) * 32768 + lane * 8;
    const unsigned short* pa1 = At + (size_t)(bm * 4 + wr * 2 + 1) * 32768 + lane * 8;
    const unsigned short* pb0 = Bt + (size_t)(bn * 4 + wc * 2 + 0) * 32768 + lane * 8;
    const unsigned short* pb1 = Bt + (size_t)(bn * 4 + wc * 2 + 1) * 32768 + lane * 8;

    f32x16 acc[2][2] = {};

    bf16x8 a0[2], a1[2], b0[2], b1[2];
#pragma unroll
    for (int p = 0; p < 2; ++p) {
        a0[p] = *(const bf16x8*)(pa0 + p * 512);
        a1[p] = *(const bf16x8*)(pa1 + p * 512);
        b0[p] = *(const bf16x8*)(pb0 + p * 512);
        b1[p] = *(const bf16x8*)(pb1 + p * 512);
    }

#pragma unroll
    for (int ks = 0; ks < 64; ++ks) {
        const int slot = ks & 1;
        bf16x8 ca0 = a0[slot], ca1 = a1[slot], cb0 = b0[slot], cb1 = b1[slot];
        if (ks + 2 < 64) {
            a0[slot] = *(const bf16x8*)(pa0 + (ks + 2) * 512);
            a1[slot] = *(const bf16x8*)(pa1 + (ks + 2) * 512);
            b0[slot] = *(const bf16x8*)(pb0 + (ks + 2) * 512);
            b1[slot] = *(const bf16x8*)(pb1 + (ks + 2) * 512);
        }
        acc[0][0] = __builtin_amdgcn_mfma_f32_32x32x16_bf16(ca0, cb0, acc[0][0], 0, 0, 0);
        acc[0][1] = __builtin_amdgcn_mfma_f32_32x32x16_bf16(ca0, cb1, acc[0][1], 0, 0, 0);
        acc[1][0] = __builtin_amdgcn_mfma_f32_32x32x16_bf16(ca1, cb0, acc[1][0], 0, 0, 0);
        acc[1][1] = __builtin_amdgcn_mfma_f32_32x32x16_bf16(ca1, cb1, acc[1][1], 0, 0, 0);
    }

    // Epilogue (identical to R3, verified): C/D col = lane&31,
    // row = (reg&3) + 8*(reg>>2) + 4*half.
    const int section = (bn * 128) >> 10;
    const int nloc0   = (bn * 128 - section * 1024) + wc * 64;
    const float* bias = (section == 0) ? bq : (section == 1) ? bk : bv;
    float* outsec = out + (size_t)section * (4u * 16u * 4096u * 64u);

#pragma unroll
    for (int jb = 0; jb < 2; ++jb) {
        int f = nloc0 + jb * 32 + r5;
        float bval = bias[f];
        int h = f >> 6, d = f & 63;
        size_t hb = (size_t)h * (4096u * 64u);
#pragma unroll
        for (int ib = 0; ib < 2; ++ib) {
            int mbase = bm * 128 + wr * 64 + ib * 32 + 4 * half;
#pragma unroll
            for (int reg = 0; reg < 16; ++reg) {
                int m = mbase + (reg & 3) + 8 * (reg >> 2);
                int b = m >> 12, s = m & 4095;
                outsec[(size_t)b * (16u * 4096u * 64u) + hb + (size_t)s * 64u + d] =
                    acc[ib][jb][reg] + bval;
            }
        }
    }
}

extern "C" void kernel_launch(void* const* d_in, const int* in_sizes, int n_in,
                              void* d_out, int out_size, void* d_ws, size_t ws_size,
                              hipStream_t stream) {
    const float* hs = (const float*)d_in[0];
    const float* Wq = (const float*)d_in[1];
    const float* bq = (const float*)d_in[2];
    const float* Wk = (const float*)d_in[3];
    const float* bk = (const float*)d_in[4];
    const float* Wv = (const float*)d_in[5];
    const float* bv = (const float*)d_in[6];
    float* out = (float*)d_out;

    unsigned short* Atld = (unsigned short*)d_ws;            // 512*64*512 ush = 32 MiB
    unsigned short* Btld = Atld + (size_t)M_TOT * K_TOT;     // 96*64*512  ush =  6 MiB

    convert_hidden<<<512, 256, 0, stream>>>(hs, Atld);
    convert_weights<<<96, 256, 0, stream>>>(Wq, Wk, Wv, Btld);
    qkv_gemm<<<dim3(M_TOT / 128, N_TOT / 128), 256, 0, stream>>>(Atld, Btld, bq, bk, bv, out);
}